// Round 6
// baseline (435.379 us; speedup 1.0000x reference)
//
#include <hip/hip_runtime.h>
#include <hip/hip_bf16.h>
#include <math.h>

#define T_TOK 2048
#define HD 1024
#define ID 2048
#define NE 8

typedef __attribute__((ext_vector_type(8))) short s16x8;
typedef __attribute__((ext_vector_type(8))) unsigned short u16x8;
typedef __attribute__((ext_vector_type(4))) float f32x4;
typedef __attribute__((ext_vector_type(4))) unsigned short u16x4;

__device__ __forceinline__ unsigned short f2bf(float f) {
  union { float f; unsigned u; } v; v.f = f;
  unsigned r = v.u + 0x7FFFu + ((v.u >> 16) & 1u);   // RNE
  return (unsigned short)(r >> 16);
}

// 8 fp32 -> bf16x8 fragment; scalar casts fuse to v_cvt_pk_bf16_f32
__device__ __forceinline__ s16x8 cvt8(float4 a, float4 b) {
  union { s16x8 v; __hip_bfloat16 h[8]; } u;
  u.h[0] = __float2bfloat16(a.x); u.h[1] = __float2bfloat16(a.y);
  u.h[2] = __float2bfloat16(a.z); u.h[3] = __float2bfloat16(a.w);
  u.h[4] = __float2bfloat16(b.x); u.h[5] = __float2bfloat16(b.y);
  u.h[6] = __float2bfloat16(b.z); u.h[7] = __float2bfloat16(b.w);
  return u.v;
}

#define GLOAD16(gsrc, ldst) \
  __builtin_amdgcn_global_load_lds((const __attribute__((address_space(1))) void*)(gsrc), \
                                   (__attribute__((address_space(3))) void*)(ldst), 16, 0, 0)

// ---------------- router: one wave per token ----------------
__global__ void router_k(const float* __restrict__ x, const float* __restrict__ gate,
                         int* __restrict__ cnt, int* __restrict__ tok,
                         float* __restrict__ wt, int* __restrict__ inv) {
  int wid = threadIdx.x >> 6, lane = threadIdx.x & 63;
  int t = blockIdx.x * 4 + wid;
  const float* xr = x + (size_t)t * HD;
  float acc[NE];
#pragma unroll
  for (int e = 0; e < NE; e++) acc[e] = 0.f;
  for (int h = lane; h < HD; h += 64) {
    float xv = xr[h];
#pragma unroll
    for (int e = 0; e < NE; e++) acc[e] += xv * gate[e * HD + h];
  }
#pragma unroll
  for (int e = 0; e < NE; e++)
    for (int off = 32; off; off >>= 1) acc[e] += __shfl_xor(acc[e], off);
  int i0 = 0;
#pragma unroll
  for (int e = 1; e < NE; e++) if (acc[e] > acc[i0]) i0 = e;
  int i1 = (i0 == 0) ? 1 : 0;
#pragma unroll
  for (int e = 0; e < NE; e++) if (e != i0 && acc[e] > acc[i1]) i1 = e;
  float w0 = 1.f / (1.f + expf(acc[i1] - acc[i0]));
  float w1 = 1.f - w0;
  if (lane == 0) {
    int p0 = atomicAdd(&cnt[i0], 1);
    tok[i0 * T_TOK + p0] = t; wt[i0 * T_TOK + p0] = w0;
    inv[2 * t] = (i0 << 16) | p0;
    int p1 = atomicAdd(&cnt[i1], 1);
    tok[i1 * T_TOK + p1] = t; wt[i1 * T_TOK + p1] = w1;
    inv[2 * t + 1] = (i1 << 16) | p1;
  }
}

__global__ void prefix_k(const int* __restrict__ cnt, int* __restrict__ offs) {
  if (threadIdx.x == 0) {
    int s = 0;
    for (int e = 0; e < NE; e++) { offs[e] = s; s += cnt[e]; }
  }
}

// gather token rows (fp32 -> bf16), compacted by expert
__global__ void gather_k(const float* __restrict__ x, const int* __restrict__ cnt,
                         const int* __restrict__ offs, const int* __restrict__ tok,
                         unsigned short* __restrict__ Xg) {
  int e = blockIdx.x >> 11, slot = blockIdx.x & 2047;
  if (slot >= cnt[e]) return;
  int t = tok[e * T_TOK + slot];
  int row = offs[e] + slot;
  int c = threadIdx.x * 4;
  float4 f = *(const float4*)(x + (size_t)t * HD + c);
  u16x4 o; o.x = f2bf(f.x); o.y = f2bf(f.y); o.z = f2bf(f.z); o.w = f2bf(f.w);
  *(u16x4*)(Xg + (size_t)row * HD + c) = o;
}

// ---------------- grouped GEMM1: act = w * silu(Xg@w1^T) * (Xg@w3^T) ----------------
// BM=256 BN=64 BK=32, 512 thr (8 waves 4x2).
// A (bf16): chunk-major LDS [16 chunks][16 rows x 4 gran x 16B], 2-deep.
// B1/B2 (fp32): column-major granules [8 g][64 rows][16B], 3-deep.
// Counted vmcnt(2) at barriers (never 0 in steady state).
__global__ __launch_bounds__(512, 4) void gemm1_k(
    const unsigned short* __restrict__ Xg, const float* __restrict__ w1,
    const float* __restrict__ w3, const int* __restrict__ cnt,
    const int* __restrict__ offs, const float* __restrict__ wt,
    unsigned short* __restrict__ act) {
  int bid = blockIdx.x;
  int e = bid & 7;                       // expert == XCD (L2 pinning)
  int r2 = bid >> 3;
  int nt = r2 & 31, mt = r2 >> 5;        // nt 0..31, mt 0..7
  int count = cnt[e];
  if (mt * 256 >= count) return;
  int i0 = nt * 64;
  int rbase = offs[e] + mt * 256;
  const float* W1 = w1 + (size_t)e * ID * HD;
  const float* W3 = w3 + (size_t)e * ID * HD;

  __shared__ __align__(16) unsigned short Ab[2][256 * 32];  // 16KB x2
  __shared__ __align__(16) float B1b[3][64 * 32];           // 8KB x3
  __shared__ __align__(16) float B2b[3][64 * 32];           // 8KB x3

  int tid = threadIdx.x;
  int wid = tid >> 6, lane = tid & 63;
  int wr = wid >> 1, wc = wid & 1;       // 4x2 wave grid, wave tile 64x32
  int l15 = lane & 15, hi = lane >> 4;

  // A staging: wave stages chunks q=2w,2w+1; lane = gran*16 + rowInChunk
  const unsigned short* aS[2];
#pragma unroll
  for (int c = 0; c < 2; c++)
    aS[c] = Xg + (size_t)(rbase + (2 * wid + c) * 16 + l15) * HD + hi * 8;
  int aD[2];
#pragma unroll
  for (int c = 0; c < 2; c++) aD[c] = (2 * wid + c) * 512 + lane * 8;
  // B staging: wave w stages granule g=w; lane = row
  const float* b1S = W1 + (size_t)(i0 + lane) * HD + wid * 4;
  const float* b2S = W3 + (size_t)(i0 + lane) * HD + wid * 4;
  int bD = wid * 256 + lane * 4;

  f32x4 accg[4][2], accu[4][2];
#pragma unroll
  for (int m = 0; m < 4; m++)
#pragma unroll
    for (int n = 0; n < 2; n++) {
      accg[m][n] = (f32x4){0.f, 0.f, 0.f, 0.f};
      accu[m][n] = (f32x4){0.f, 0.f, 0.f, 0.f};
    }

#define STAGE_A1(buf, k0) do { \
    GLOAD16(aS[0] + (k0), &Ab[buf][aD[0]]); \
    GLOAD16(aS[1] + (k0), &Ab[buf][aD[1]]); } while (0)
#define STAGE_B1(buf, k0) do { \
    GLOAD16(b1S + (k0), &B1b[buf][bD]); \
    GLOAD16(b2S + (k0), &B2b[buf][bD]); } while (0)

  // prologue: A(0), B(0), B(1)  (A-first ordering makes vmcnt(2) drain A(t)+B(t))
  STAGE_A1(0, 0);
  STAGE_B1(0, 0);
  STAGE_B1(1, 32);

  for (int t = 0; t < 32; ++t) {
    if (t < 31) asm volatile("s_waitcnt vmcnt(2)" ::: "memory");
    else        asm volatile("s_waitcnt vmcnt(0)" ::: "memory");
    __builtin_amdgcn_s_barrier();
    if (t < 31) STAGE_A1((t + 1) & 1, (t + 1) * 32);
    if (t < 30) STAGE_B1((t + 2) % 3, (t + 2) * 32);
    int ab = t & 1, bb = t % 3;
    s16x8 a[4];
#pragma unroll
    for (int m = 0; m < 4; m++)
      a[m] = *(const s16x8*)&Ab[ab][(wr * 4 + m) * 512 + hi * 128 + l15 * 8];
#pragma unroll
    for (int n = 0; n < 2; n++) {
      int rB = (wc * 32 + n * 16 + l15) * 4;
      float4 q0 = *(const float4*)&B1b[bb][(2 * hi) * 256 + rB];
      float4 q1 = *(const float4*)&B1b[bb][(2 * hi + 1) * 256 + rB];
      s16x8 b1 = cvt8(q0, q1);
      float4 q2 = *(const float4*)&B2b[bb][(2 * hi) * 256 + rB];
      float4 q3 = *(const float4*)&B2b[bb][(2 * hi + 1) * 256 + rB];
      s16x8 b2 = cvt8(q2, q3);
#pragma unroll
      for (int m = 0; m < 4; m++) {
        accg[m][n] = __builtin_amdgcn_mfma_f32_16x16x32_bf16(a[m], b1, accg[m][n], 0, 0, 0);
        accu[m][n] = __builtin_amdgcn_mfma_f32_16x16x32_bf16(a[m], b2, accu[m][n], 0, 0, 0);
      }
    }
  }

  // epilogue: w * silu(g) * u -> bf16 act (C/D map: col=lane&15, row=(lane>>4)*4+reg)
#pragma unroll
  for (int m = 0; m < 4; m++)
#pragma unroll
    for (int r = 0; r < 4; r++) {
      int rl = mt * 256 + wr * 64 + m * 16 + hi * 4 + r;
      if (rl < count) {
        float w = wt[e * T_TOK + rl];
#pragma unroll
        for (int n = 0; n < 2; n++) {
          float g = accg[m][n][r], u = accu[m][n][r];
          float s = (g / (1.f + expf(-g))) * u * w;
          act[(size_t)(offs[e] + rl) * ID + i0 + wc * 32 + n * 16 + l15] = f2bf(s);
        }
      }
    }
#undef STAGE_A1
#undef STAGE_B1
}

// ---------------- grouped GEMM2: ye = act @ w2^T ----------------
// BM=128 BN=64 BK=32, K=2048, 256 thr (4 waves 2x2). A 2-deep, B 4-deep.
__global__ __launch_bounds__(256, 3) void gemm2_k(
    const unsigned short* __restrict__ act, const float* __restrict__ w2,
    const int* __restrict__ cnt, const int* __restrict__ offs,
    float* __restrict__ ye) {
  int bid = blockIdx.x;
  int e = bid & 7;
  int r2 = bid >> 3;
  int nt = r2 & 15, mt = r2 >> 4;        // nt 0..15, mt 0..15
  int count = cnt[e];
  if (mt * 128 >= count) return;
  int h0 = nt * 64;
  int rbase = offs[e] + mt * 128;
  const float* W2 = w2 + (size_t)e * HD * ID;   // [1024][2048]

  __shared__ __align__(16) unsigned short Ab[2][128 * 32];  // 8KB x2
  __shared__ __align__(16) float Bb[4][64 * 32];            // 8KB x4

  int tid = threadIdx.x;
  int wid = tid >> 6, lane = tid & 63;
  int wr = wid >> 1, wc = wid & 1;
  int l15 = lane & 15, hi = lane >> 4;

  const unsigned short* aS[2];
#pragma unroll
  for (int c = 0; c < 2; c++)
    aS[c] = act + (size_t)(rbase + (2 * wid + c) * 16 + l15) * ID + hi * 8;
  int aD[2];
#pragma unroll
  for (int c = 0; c < 2; c++) aD[c] = (2 * wid + c) * 512 + lane * 8;
  const float* bS[2];
#pragma unroll
  for (int c = 0; c < 2; c++)
    bS[c] = W2 + (size_t)(h0 + lane) * ID + (2 * wid + c) * 4;
  int bD[2];
#pragma unroll
  for (int c = 0; c < 2; c++) bD[c] = (2 * wid + c) * 256 + lane * 4;

  f32x4 acc[4][2];
#pragma unroll
  for (int m = 0; m < 4; m++)
#pragma unroll
    for (int n = 0; n < 2; n++) acc[m][n] = (f32x4){0.f, 0.f, 0.f, 0.f};

#define STAGE_A2(buf, k0) do { \
    GLOAD16(aS[0] + (k0), &Ab[buf][aD[0]]); \
    GLOAD16(aS[1] + (k0), &Ab[buf][aD[1]]); } while (0)
#define STAGE_B2(buf, k0) do { \
    GLOAD16(bS[0] + (k0), &Bb[buf][bD[0]]); \
    GLOAD16(bS[1] + (k0), &Bb[buf][bD[1]]); } while (0)

  // prologue order B0,B1,A0,B2 -> uniform vmcnt(2) from t=0
  STAGE_B2(0, 0);
  STAGE_B2(1, 32);
  STAGE_A2(0, 0);
  STAGE_B2(2, 64);

  for (int t = 0; t < 64; ++t) {
    if (t < 62) asm volatile("s_waitcnt vmcnt(2)" ::: "memory");
    else        asm volatile("s_waitcnt vmcnt(0)" ::: "memory");
    __builtin_amdgcn_s_barrier();
    if (t < 63) STAGE_A2((t + 1) & 1, (t + 1) * 32);
    if (t < 61) STAGE_B2((t + 3) & 3, (t + 3) * 32);
    int ab = t & 1, bb = t & 3;
    s16x8 a[4];
#pragma unroll
    for (int m = 0; m < 4; m++)
      a[m] = *(const s16x8*)&Ab[ab][(wr * 4 + m) * 512 + hi * 128 + l15 * 8];
#pragma unroll
    for (int n = 0; n < 2; n++) {
      int rB = (wc * 32 + n * 16 + l15) * 4;
      float4 q0 = *(const float4*)&Bb[bb][(2 * hi) * 256 + rB];
      float4 q1 = *(const float4*)&Bb[bb][(2 * hi + 1) * 256 + rB];
      s16x8 b = cvt8(q0, q1);
#pragma unroll
      for (int m = 0; m < 4; m++)
        acc[m][n] = __builtin_amdgcn_mfma_f32_16x16x32_bf16(a[m], b, acc[m][n], 0, 0, 0);
    }
  }

#pragma unroll
  for (int m = 0; m < 4; m++)
#pragma unroll
    for (int r = 0; r < 4; r++) {
      int slot = mt * 128 + wr * 64 + m * 16 + hi * 4 + r;
      if (slot < count) {
#pragma unroll
        for (int n = 0; n < 2; n++)
          ye[(size_t)(offs[e] + slot) * HD + h0 + wc * 32 + n * 16 + l15] = acc[m][n][r];
      }
    }
#undef STAGE_A2
#undef STAGE_B2
}

// ---------------- combine: out[t] = ye[slot0] + ye[slot1] ----------------
__global__ void combine_k(const float* __restrict__ ye, const int* __restrict__ inv,
                          const int* __restrict__ offs, float* __restrict__ out) {
  int t = blockIdx.x;
  int c = threadIdx.x * 4;
  int v0 = inv[2 * t], v1 = inv[2 * t + 1];
  int r0 = offs[v0 >> 16] + (v0 & 0xFFFF);
  int r1 = offs[v1 >> 16] + (v1 & 0xFFFF);
  float4 a = *(const float4*)(ye + (size_t)r0 * HD + c);
  float4 b = *(const float4*)(ye + (size_t)r1 * HD + c);
  float4 o = {a.x + b.x, a.y + b.y, a.z + b.z, a.w + b.w};
  *(float4*)(out + (size_t)t * HD + c) = o;
}

extern "C" void kernel_launch(void* const* d_in, const int* in_sizes, int n_in,
                              void* d_out, int out_size, void* d_ws, size_t ws_size,
                              hipStream_t stream) {
  const float* x    = (const float*)d_in[0];
  const float* gate = (const float*)d_in[1];
  const float* w1   = (const float*)d_in[2];
  const float* w3   = (const float*)d_in[3];
  const float* w2   = (const float*)d_in[4];
  float* out = (float*)d_out;

  char* ws = (char*)d_ws;
  int* cnt  = (int*)(ws + 0);
  int* offs = (int*)(ws + 256);
  int* tok  = (int*)(ws + 512);                           // 64K
  float* wt = (float*)(ws + 66048);                       // 64K
  int* inv  = (int*)(ws + 131584);                        // 16K
  unsigned short* Xg  = (unsigned short*)(ws + 148480);   // 5120 x 1024 bf16 (pad rows for tail over-stage)
  unsigned short* act = (unsigned short*)(ws + 10634240); // 5120 x 2048 bf16
  float* ye = (float*)(ws + 31605760);                    // 4224 x 1024 f32 -> ends ~48.9M

  hipMemsetAsync(cnt, 0, 256, stream);

  router_k<<<T_TOK / 4, 256, 0, stream>>>(x, gate, cnt, tok, wt, inv);
  prefix_k<<<1, 64, 0, stream>>>(cnt, offs);
  gather_k<<<NE * T_TOK, 256, 0, stream>>>(x, cnt, offs, tok, Xg);
  // 1-D grids, expert = bid & 7 -> expert->XCD pinning for L2 locality
  gemm1_k<<<NE * 32 * 8, 512, 0, stream>>>(Xg, w1, w3, cnt, offs, wt, act);
  gemm2_k<<<NE * 16 * 16, 256, 0, stream>>>(act, w2, cnt, offs, ye);
  combine_k<<<T_TOK, 256, 0, stream>>>(ye, inv, offs, out);
}

// Round 7
// 390.885 us; speedup vs baseline: 1.1138x; 1.1138x over previous
//
#include <hip/hip_runtime.h>
#include <hip/hip_bf16.h>
#include <math.h>

#define T_TOK 2048
#define HD 1024
#define ID 2048
#define NE 8
#define LDA 36   // LDS row stride (bf16 elems) for [128][32] and [64][32] tiles: 72B -> 2-way max (free)

typedef __attribute__((ext_vector_type(8))) short s16x8;
typedef __attribute__((ext_vector_type(8))) unsigned short u16x8;
typedef __attribute__((ext_vector_type(4))) float f32x4;
typedef __attribute__((ext_vector_type(4))) unsigned short u16x4;

__device__ __forceinline__ unsigned short f2bf(float f) {
  union { float f; unsigned u; } v; v.f = f;
  unsigned r = v.u + 0x7FFFu + ((v.u >> 16) & 1u);   // RNE
  return (unsigned short)(r >> 16);
}

__device__ __forceinline__ u16x8 pack8(float4 a, float4 b) {
  u16x8 v;
  v[0] = f2bf(a.x); v[1] = f2bf(a.y); v[2] = f2bf(a.z); v[3] = f2bf(a.w);
  v[4] = f2bf(b.x); v[5] = f2bf(b.y); v[6] = f2bf(b.z); v[7] = f2bf(b.w);
  return v;
}

#define PHASE_BARRIER() do { \
  asm volatile("s_waitcnt lgkmcnt(0)" ::: "memory"); \
  __builtin_amdgcn_s_barrier(); \
  __builtin_amdgcn_sched_barrier(0); } while (0)

// ---------------- router: one wave per token ----------------
__global__ void router_k(const float* __restrict__ x, const float* __restrict__ gate,
                         int* __restrict__ cnt, int* __restrict__ tok,
                         float* __restrict__ wt, int* __restrict__ inv) {
  int wid = threadIdx.x >> 6, lane = threadIdx.x & 63;
  int t = blockIdx.x * 4 + wid;
  const float* xr = x + (size_t)t * HD;
  float acc[NE];
#pragma unroll
  for (int e = 0; e < NE; e++) acc[e] = 0.f;
  for (int h = lane; h < HD; h += 64) {
    float xv = xr[h];
#pragma unroll
    for (int e = 0; e < NE; e++) acc[e] += xv * gate[e * HD + h];
  }
#pragma unroll
  for (int e = 0; e < NE; e++)
    for (int off = 32; off; off >>= 1) acc[e] += __shfl_xor(acc[e], off);
  int i0 = 0;
#pragma unroll
  for (int e = 1; e < NE; e++) if (acc[e] > acc[i0]) i0 = e;
  int i1 = (i0 == 0) ? 1 : 0;
#pragma unroll
  for (int e = 0; e < NE; e++) if (e != i0 && acc[e] > acc[i1]) i1 = e;
  float w0 = 1.f / (1.f + expf(acc[i1] - acc[i0]));
  float w1 = 1.f - w0;
  if (lane == 0) {
    int p0 = atomicAdd(&cnt[i0], 1);
    tok[i0 * T_TOK + p0] = t; wt[i0 * T_TOK + p0] = w0;
    inv[2 * t] = (i0 << 16) | p0;
    int p1 = atomicAdd(&cnt[i1], 1);
    tok[i1 * T_TOK + p1] = t; wt[i1 * T_TOK + p1] = w1;
    inv[2 * t + 1] = (i1 << 16) | p1;
  }
}

__global__ void prefix_k(const int* __restrict__ cnt, int* __restrict__ offs) {
  if (threadIdx.x == 0) {
    int s = 0;
    for (int e = 0; e < NE; e++) { offs[e] = s; s += cnt[e]; }
  }
}

// gather token rows (fp32 -> bf16), compacted by expert
__global__ void gather_k(const float* __restrict__ x, const int* __restrict__ cnt,
                         const int* __restrict__ offs, const int* __restrict__ tok,
                         unsigned short* __restrict__ Xg) {
  int e = blockIdx.x >> 11, slot = blockIdx.x & 2047;
  if (slot >= cnt[e]) return;
  int t = tok[e * T_TOK + slot];
  int row = offs[e] + slot;
  int c = threadIdx.x * 4;
  float4 f = *(const float4*)(x + (size_t)t * HD + c);
  u16x4 o; o.x = f2bf(f.x); o.y = f2bf(f.y); o.z = f2bf(f.z); o.w = f2bf(f.w);
  *(u16x4*)(Xg + (size_t)row * HD + c) = o;
}

// ---------------- grouped GEMM1: act = w * silu(Xg@w1^T) * (Xg@w3^T) ----------------
// BM=128 BN=64 BK=32, 256 thr (4 waves 2x2, wave tile 64x32).
// A: reg-staged bf16, LDS dbuf (1-phase flight, L2-warm).
// B1/B2: reg-staged fp32->bf16, LDS ring-3 (2-phase flight, counted drains via ds_write reg deps).
__global__ __launch_bounds__(256, 3) void gemm1_k(
    const unsigned short* __restrict__ Xg, const float* __restrict__ w1,
    const float* __restrict__ w3, const int* __restrict__ cnt,
    const int* __restrict__ offs, const float* __restrict__ wt,
    unsigned short* __restrict__ act) {
  int bid = blockIdx.x;
  int e = bid & 7;                       // expert == XCD (L2 pinning)
  int r2 = bid >> 3;
  int nt = r2 & 31, mt = r2 >> 5;        // nt 0..31, mt 0..15
  int count = cnt[e];
  if (mt * 128 >= count) return;
  int i0 = nt * 64;
  int rbase = offs[e] + mt * 128;
  const float* W1 = w1 + (size_t)e * ID * HD;
  const float* W3 = w3 + (size_t)e * ID * HD;

  __shared__ __align__(16) unsigned short Ab[2][128 * LDA];   // 9 KB x2
  __shared__ __align__(16) unsigned short B1b[3][64 * LDA];   // 4.5 KB x3
  __shared__ __align__(16) unsigned short B2b[3][64 * LDA];   // 4.5 KB x3

  int tid = threadIdx.x;
  int wid = tid >> 6, lane = tid & 63;
  int wr = wid >> 1, wc = wid & 1;
  int l15 = lane & 15, hi = lane >> 4;

  // staging maps
  int rowA = tid >> 1, colA = (tid & 1) * 16;        // A: 128 rows x 2 half-rows of 16
  const unsigned short* aSrc = Xg + (size_t)(rbase + rowA) * HD + colA;
  int aDst = rowA * LDA + colA;
  int rowB = tid >> 2, colB = (tid & 3) * 8;         // B: 64 rows x 4 chunks of 8
  const float* s1 = W1 + (size_t)(i0 + rowB) * HD + colB;
  const float* s2 = W3 + (size_t)(i0 + rowB) * HD + colB;
  int bDst = rowB * LDA + colB;

  // fragment read offsets
  int aOff[4], bOff[2];
#pragma unroll
  for (int m = 0; m < 4; m++) aOff[m] = (wr * 64 + m * 16 + l15) * LDA + hi * 8;
#pragma unroll
  for (int n = 0; n < 2; n++) bOff[n] = (wc * 32 + n * 16 + l15) * LDA + hi * 8;

  f32x4 accg[4][2], accu[4][2];
#pragma unroll
  for (int m = 0; m < 4; m++)
#pragma unroll
    for (int n = 0; n < 2; n++) {
      accg[m][n] = (f32x4){0.f, 0.f, 0.f, 0.f};
      accu[m][n] = (f32x4){0.f, 0.f, 0.f, 0.f};
    }

  // ---- prologue: tile0 -> LDS; Ar1 <- A(1); Br0 <- B(1); Br1 <- B(2)
  u16x8 tA0 = *(const u16x8*)aSrc, tA1 = *(const u16x8*)(aSrc + 8);
  float4 q10 = *(const float4*)s1, q11 = *(const float4*)(s1 + 4);
  float4 q20 = *(const float4*)s2, q21 = *(const float4*)(s2 + 4);
  *(u16x8*)&Ab[0][aDst] = tA0; *(u16x8*)&Ab[0][aDst + 8] = tA1;
  *(u16x8*)&B1b[0][bDst] = pack8(q10, q11);
  *(u16x8*)&B2b[0][bDst] = pack8(q20, q21);
  u16x8 ar1a = *(const u16x8*)(aSrc + 32), ar1b = *(const u16x8*)(aSrc + 40);
  float4 b1x0 = *(const float4*)(s1 + 32), b1y0 = *(const float4*)(s1 + 36);
  float4 b2x0 = *(const float4*)(s2 + 32), b2y0 = *(const float4*)(s2 + 36);
  float4 b1x1 = *(const float4*)(s1 + 64), b1y1 = *(const float4*)(s1 + 68);
  float4 b2x1 = *(const float4*)(s2 + 64), b2y1 = *(const float4*)(s2 + 68);
  u16x8 ar0a, ar0b;
  PHASE_BARRIER();

#define G1_COMPUTE(AB, BB) do { \
    s16x8 a_[4], f1_[2], f2_[2]; \
    _Pragma("unroll") \
    for (int m = 0; m < 4; m++) a_[m] = *(const s16x8*)&Ab[AB][aOff[m]]; \
    _Pragma("unroll") \
    for (int n = 0; n < 2; n++) { \
      f1_[n] = *(const s16x8*)&B1b[BB][bOff[n]]; \
      f2_[n] = *(const s16x8*)&B2b[BB][bOff[n]]; \
    } \
    _Pragma("unroll") \
    for (int m = 0; m < 4; m++) \
      _Pragma("unroll") \
      for (int n = 0; n < 2; n++) { \
        accg[m][n] = __builtin_amdgcn_mfma_f32_16x16x32_bf16(a_[m], f1_[n], accg[m][n], 0, 0, 0); \
        accu[m][n] = __builtin_amdgcn_mfma_f32_16x16x32_bf16(a_[m], f2_[n], accu[m][n], 0, 0, 0); \
      } \
  } while (0)

  int cur = 0;   // B ring read index
  for (int tt = 0; tt < 32; tt += 2) {
    // ---- phase t = tt (even): write A1/B(set0); load A0<-A(t+2), B(set0)<-B(t+3); read Ab[0],B[cur]
    {
      int t = tt;
      int wb = cur + 1; if (wb == 3) wb = 0;
      // ds_write (auto vmcnt counted: drains through this tile's regs, leaves newer loads in flight)
      *(u16x8*)&Ab[1][aDst] = ar1a; *(u16x8*)&Ab[1][aDst + 8] = ar1b;
      *(u16x8*)&B1b[wb][bDst] = pack8(b1x0, b1y0);
      *(u16x8*)&B2b[wb][bDst] = pack8(b2x0, b2y0);
      if (t + 2 < 32) {
        ar0a = *(const u16x8*)(aSrc + (t + 2) * 32);
        ar0b = *(const u16x8*)(aSrc + (t + 2) * 32 + 8);
      }
      if (t + 3 < 32) {
        b1x0 = *(const float4*)(s1 + (t + 3) * 32); b1y0 = *(const float4*)(s1 + (t + 3) * 32 + 4);
        b2x0 = *(const float4*)(s2 + (t + 3) * 32); b2y0 = *(const float4*)(s2 + (t + 3) * 32 + 4);
      }
      G1_COMPUTE(0, cur);
      PHASE_BARRIER();
      cur = wb;
    }
    // ---- phase t = tt+1 (odd): write A0/B(set1); load A1<-A(t+2), B(set1)<-B(t+3); read Ab[1],B[cur]
    {
      int t = tt + 1;
      int wb = cur + 1; if (wb == 3) wb = 0;
      if (t + 1 < 32) {
        *(u16x8*)&Ab[0][aDst] = ar0a; *(u16x8*)&Ab[0][aDst + 8] = ar0b;
        *(u16x8*)&B1b[wb][bDst] = pack8(b1x1, b1y1);
        *(u16x8*)&B2b[wb][bDst] = pack8(b2x1, b2y1);
      }
      if (t + 2 < 32) {
        ar1a = *(const u16x8*)(aSrc + (t + 2) * 32);
        ar1b = *(const u16x8*)(aSrc + (t + 2) * 32 + 8);
      }
      if (t + 3 < 32) {
        b1x1 = *(const float4*)(s1 + (t + 3) * 32); b1y1 = *(const float4*)(s1 + (t + 3) * 32 + 4);
        b2x1 = *(const float4*)(s2 + (t + 3) * 32); b2y1 = *(const float4*)(s2 + (t + 3) * 32 + 4);
      }
      G1_COMPUTE(1, cur);
      PHASE_BARRIER();
      cur = wb;
    }
  }
#undef G1_COMPUTE

  // epilogue: w * silu(g) * u -> bf16 act (C/D map: col=lane&15, row=(lane>>4)*4+reg)
#pragma unroll
  for (int m = 0; m < 4; m++)
#pragma unroll
    for (int r = 0; r < 4; r++) {
      int rl = mt * 128 + wr * 64 + m * 16 + hi * 4 + r;
      if (rl < count) {
        float w = wt[e * T_TOK + rl];
#pragma unroll
        for (int n = 0; n < 2; n++) {
          float g = accg[m][n][r], u = accu[m][n][r];
          float s = (g / (1.f + expf(-g))) * u * w;
          act[(size_t)(offs[e] + rl) * ID + i0 + wc * 32 + n * 16 + l15] = f2bf(s);
        }
      }
    }
}

// ---------------- grouped GEMM2: ye_s = act @ w2^T (split-K x2) ----------------
// BM=128 BN=64 BK=32, K-slice 1024 per split, same pipeline, single B tensor.
__global__ __launch_bounds__(256, 4) void gemm2_k(
    const unsigned short* __restrict__ act, const float* __restrict__ w2,
    const int* __restrict__ cnt, const int* __restrict__ offs,
    float* __restrict__ ye0, float* __restrict__ ye1) {
  int bid = blockIdx.x;
  int e = bid & 7;
  int r2 = bid >> 3;
  int nt = r2 & 15;
  int mt = (r2 >> 4) & 15;
  int split = r2 >> 8;
  int count = cnt[e];
  if (mt * 128 >= count) return;
  int h0 = nt * 64;
  int kbase = split * 1024;
  int rbase = offs[e] + mt * 128;
  const float* W2 = w2 + (size_t)e * HD * ID;
  float* ye = split ? ye1 : ye0;

  __shared__ __align__(16) unsigned short Ab[2][128 * LDA];
  __shared__ __align__(16) unsigned short Bb[3][64 * LDA];

  int tid = threadIdx.x;
  int wid = tid >> 6, lane = tid & 63;
  int wr = wid >> 1, wc = wid & 1;
  int l15 = lane & 15, hi = lane >> 4;

  int rowA = tid >> 1, colA = (tid & 1) * 16;
  const unsigned short* aSrc = act + (size_t)(rbase + rowA) * ID + kbase + colA;
  int aDst = rowA * LDA + colA;
  int rowB = tid >> 2, colB = (tid & 3) * 8;
  const float* sB = W2 + (size_t)(h0 + rowB) * ID + kbase + colB;
  int bDst = rowB * LDA + colB;

  int aOff[4], bOff[2];
#pragma unroll
  for (int m = 0; m < 4; m++) aOff[m] = (wr * 64 + m * 16 + l15) * LDA + hi * 8;
#pragma unroll
  for (int n = 0; n < 2; n++) bOff[n] = (wc * 32 + n * 16 + l15) * LDA + hi * 8;

  f32x4 acc[4][2];
#pragma unroll
  for (int m = 0; m < 4; m++)
#pragma unroll
    for (int n = 0; n < 2; n++) acc[m][n] = (f32x4){0.f, 0.f, 0.f, 0.f};

  u16x8 tA0 = *(const u16x8*)aSrc, tA1 = *(const u16x8*)(aSrc + 8);
  float4 q0 = *(const float4*)sB, q1 = *(const float4*)(sB + 4);
  *(u16x8*)&Ab[0][aDst] = tA0; *(u16x8*)&Ab[0][aDst + 8] = tA1;
  *(u16x8*)&Bb[0][bDst] = pack8(q0, q1);
  u16x8 ar1a = *(const u16x8*)(aSrc + 32), ar1b = *(const u16x8*)(aSrc + 40);
  float4 bx0 = *(const float4*)(sB + 32), by0 = *(const float4*)(sB + 36);
  float4 bx1 = *(const float4*)(sB + 64), by1 = *(const float4*)(sB + 68);
  u16x8 ar0a, ar0b;
  PHASE_BARRIER();

#define G2_COMPUTE(AB, BB) do { \
    s16x8 a_[4], f_[2]; \
    _Pragma("unroll") \
    for (int m = 0; m < 4; m++) a_[m] = *(const s16x8*)&Ab[AB][aOff[m]]; \
    _Pragma("unroll") \
    for (int n = 0; n < 2; n++) f_[n] = *(const s16x8*)&Bb[BB][bOff[n]]; \
    _Pragma("unroll") \
    for (int m = 0; m < 4; m++) \
      _Pragma("unroll") \
      for (int n = 0; n < 2; n++) \
        acc[m][n] = __builtin_amdgcn_mfma_f32_16x16x32_bf16(a_[m], f_[n], acc[m][n], 0, 0, 0); \
  } while (0)

  int cur = 0;
  for (int tt = 0; tt < 32; tt += 2) {
    {
      int t = tt;
      int wb = cur + 1; if (wb == 3) wb = 0;
      *(u16x8*)&Ab[1][aDst] = ar1a; *(u16x8*)&Ab[1][aDst + 8] = ar1b;
      *(u16x8*)&Bb[wb][bDst] = pack8(bx0, by0);
      if (t + 2 < 32) {
        ar0a = *(const u16x8*)(aSrc + (t + 2) * 32);
        ar0b = *(const u16x8*)(aSrc + (t + 2) * 32 + 8);
      }
      if (t + 3 < 32) {
        bx0 = *(const float4*)(sB + (t + 3) * 32); by0 = *(const float4*)(sB + (t + 3) * 32 + 4);
      }
      G2_COMPUTE(0, cur);
      PHASE_BARRIER();
      cur = wb;
    }
    {
      int t = tt + 1;
      int wb = cur + 1; if (wb == 3) wb = 0;
      if (t + 1 < 32) {
        *(u16x8*)&Ab[0][aDst] = ar0a; *(u16x8*)&Ab[0][aDst + 8] = ar0b;
        *(u16x8*)&Bb[wb][bDst] = pack8(bx1, by1);
      }
      if (t + 2 < 32) {
        ar1a = *(const u16x8*)(aSrc + (t + 2) * 32);
        ar1b = *(const u16x8*)(aSrc + (t + 2) * 32 + 8);
      }
      if (t + 3 < 32) {
        bx1 = *(const float4*)(sB + (t + 3) * 32); by1 = *(const float4*)(sB + (t + 3) * 32 + 4);
      }
      G2_COMPUTE(1, cur);
      PHASE_BARRIER();
      cur = wb;
    }
  }
#undef G2_COMPUTE

#pragma unroll
  for (int m = 0; m < 4; m++)
#pragma unroll
    for (int r = 0; r < 4; r++) {
      int slot = mt * 128 + wr * 64 + m * 16 + hi * 4 + r;
      if (slot < count) {
#pragma unroll
        for (int n = 0; n < 2; n++)
          ye[(size_t)(offs[e] + slot) * HD + h0 + wc * 32 + n * 16 + l15] = acc[m][n][r];
      }
    }
}

// ---------------- combine: out[t] = sum of 2 experts x 2 K-splits ----------------
__global__ void combine_k(const float* __restrict__ ye0, const float* __restrict__ ye1,
                          const int* __restrict__ inv, const int* __restrict__ offs,
                          float* __restrict__ out) {
  int t = blockIdx.x;
  int c = threadIdx.x * 4;
  int v0 = inv[2 * t], v1 = inv[2 * t + 1];
  size_t r0 = (size_t)(offs[v0 >> 16] + (v0 & 0xFFFF)) * HD + c;
  size_t r1 = (size_t)(offs[v1 >> 16] + (v1 & 0xFFFF)) * HD + c;
  float4 a0 = *(const float4*)(ye0 + r0);
  float4 a1 = *(const float4*)(ye1 + r0);
  float4 b0 = *(const float4*)(ye0 + r1);
  float4 b1 = *(const float4*)(ye1 + r1);
  float4 o = {a0.x + a1.x + b0.x + b1.x, a0.y + a1.y + b0.y + b1.y,
              a0.z + a1.z + b0.z + b1.z, a0.w + a1.w + b0.w + b1.w};
  *(float4*)(out + (size_t)t * HD + c) = o;
}

extern "C" void kernel_launch(void* const* d_in, const int* in_sizes, int n_in,
                              void* d_out, int out_size, void* d_ws, size_t ws_size,
                              hipStream_t stream) {
  const float* x    = (const float*)d_in[0];
  const float* gate = (const float*)d_in[1];
  const float* w1   = (const float*)d_in[2];
  const float* w3   = (const float*)d_in[3];
  const float* w2   = (const float*)d_in[4];
  float* out = (float*)d_out;

  char* ws = (char*)d_ws;
  int* cnt  = (int*)(ws + 0);
  int* offs = (int*)(ws + 256);
  int* tok  = (int*)(ws + 512);                           // 64K
  float* wt = (float*)(ws + 66048);                       // 64K
  int* inv  = (int*)(ws + 131584);                        // 16K
  unsigned short* Xg  = (unsigned short*)(ws + 148480);   // 5120 x 1024 bf16 (padded rows for tail over-reads)
  unsigned short* act = (unsigned short*)(ws + 10634240); // 5120 x 2048 bf16
  float* ye0 = (float*)(ws + 31605760);                   // 4224 x 1024 f32
  float* ye1 = (float*)(ws + 48907264);                   // 4224 x 1024 f32 -> ends ~66.2M

  hipMemsetAsync(cnt, 0, 256, stream);

  router_k<<<T_TOK / 4, 256, 0, stream>>>(x, gate, cnt, tok, wt, inv);
  prefix_k<<<1, 64, 0, stream>>>(cnt, offs);
  gather_k<<<NE * T_TOK, 256, 0, stream>>>(x, cnt, offs, tok, Xg);
  // 1-D grids, expert = bid & 7 -> expert->XCD pinning for L2 locality
  gemm1_k<<<NE * 32 * 16, 256, 0, stream>>>(Xg, w1, w3, cnt, offs, wt, act);
  gemm2_k<<<NE * 16 * 16 * 2, 256, 0, stream>>>(act, w2, cnt, offs, ye0, ye1);
  combine_k<<<T_TOK, 256, 0, stream>>>(ye0, ye1, inv, offs, out);
}